// Round 1
// 6555.546 us; speedup vs baseline: 1.0135x; 1.0135x over previous
//
#include <hip/hip_runtime.h>
#include <cstdint>

#define GG   29
#define GG2  841
#define GG3  24389
#define DD   15
#define DD3  3375
#define SS   48
#define CC   16
#define NVOX (SS*SS*SS)        // 110592
#define FT_ELEMS (NVOX*CC)     // 1769472
#define WW   20                // sample window width per axis (covers 14*1.28+1+1)
#define WIN  (WW*WW*WW)        // 8000 voxels

__device__ __forceinline__ int clampi(int v, int lo, int hi) {
    return min(max(v, lo), hi);
}

// ---------------- transpose [C,S,S,S] -> [S^3, C] (for fixed-image fix sampling) ----------------
__global__ void __launch_bounds__(256) k_transpose(const float* __restrict__ f,
                                                   float* __restrict__ ft) {
    int idx = blockIdx.x * 256 + threadIdx.x;
    if (idx < FT_ELEMS) {
        int c = idx & 15;
        int v = idx >> 4;
        ft[idx] = f[c * NVOX + v];
    }
}

// ---------------- transpose [C,S,S,S] -> [8 groups][S^3][2ch] (moving image, f2 gather layout) ----
__global__ void __launch_bounds__(256) k_transpose2(const float* __restrict__ f,
                                                    float* __restrict__ ft) {
    int v = blockIdx.x * 256 + threadIdx.x;      // < NVOX (grid sized exactly)
    int cg8 = blockIdx.y;                        // 0..7
    float a = f[(2 * cg8)     * NVOX + v];
    float b = f[(2 * cg8 + 1) * NVOX + v];
    float2* o = (float2*)ft;
    o[(size_t)cg8 * NVOX + v] = make_float2(a, b);
}

// ---------------- K1: deeds cost volume (LDS-window gather) ----------------
// block = one grid point g. Stage the 20^3 voxel sample window into LDS
// (coalesced), 8 passes of 2 channels; gather trilinear from LDS with
// register-cached z-plane bilinears; accumulate SSD in LDS acc buffer.
__global__ void __launch_bounds__(256) k_cost2(const float* __restrict__ f5t,   // float2 [8][NVOX]
                                               const float* __restrict__ f0t,   // float  [NVOX][16]
                                               const float* __restrict__ alpha,
                                               float* __restrict__ dc) {
    __shared__ float2 win[WIN];          // 64 KB sample window, 2 channels
    __shared__ float  accb[DD3];         // 13.5 KB SSD accumulator
    __shared__ int    l0s[3][16];        // window-relative low corner per axis/disp
    __shared__ int    l1s[3][16];        // window-relative high corner (clamp-aware)
    __shared__ float  wts[3][16];        // lerp weight
    __shared__ int    baseS[3];          // window base (absolute voxel)
    __shared__ float  fixs[16];          // fixed-image feature at grid point

    int tid = threadIdx.x;
    int g = blockIdx.x;
    int gx = g % GG; int gy = (g / GG) % GG; int gz = g / GG2;

    // ---- setup: per-axis sample tables, window base = min(i0[j=0], 48-WW) ----
    if (tid < 48) {
        int axis = tid >> 4, j = tid & 15;
        if (j < 15) {
            int gi = (axis == 0) ? gx : (axis == 1) ? gy : gz;
            float cgv = (2.0f * gi + 1.0f) / 29.0f - 1.0f;
            float sj  = 0.4f * ((2.0f * j + 1.0f) / 15.0f - 1.0f);
            float p = ((cgv + sj + 1.0f) * 48.0f - 1.0f) * 0.5f;
            p = fminf(fmaxf(p, 0.0f), 47.0f);
            float fl = floorf(p);
            int i0 = (int)fl;
            // j = 0 gives the (monotone) minimum index for this axis
            float s0 = 0.4f * (1.0f / 15.0f - 1.0f);
            float p0 = ((cgv + s0 + 1.0f) * 48.0f - 1.0f) * 0.5f;
            p0 = fminf(fmaxf(p0, 0.0f), 47.0f);
            int b = min((int)floorf(p0), SS - WW);
            l0s[axis][j] = i0 - b;
            l1s[axis][j] = min(i0 + 1, 47) - b;
            wts[axis][j] = p - fl;
            if (j == 0) baseS[axis] = b;
        }
    }
    if (tid < CC) {
        // fixed-image feature at the (unshifted) grid point, channel = tid
        int giv[3] = {gx, gy, gz};
        int i0[3]; float w[3];
        #pragma unroll
        for (int a = 0; a < 3; ++a) {
            float cgv = (2.0f * giv[a] + 1.0f) / 29.0f - 1.0f;
            float p = ((cgv + 1.0f) * 48.0f - 1.0f) * 0.5f;
            p = fminf(fmaxf(p, 0.0f), 47.0f);
            float fl = floorf(p);
            i0[a] = (int)fl; w[a] = p - fl;
        }
        int x0 = i0[0], y0 = i0[1], z0 = i0[2];
        int x1 = min(x0 + 1, 47), y1 = min(y0 + 1, 47), z1 = min(z0 + 1, 47);
        float wx = w[0], wy = w[1], wz = w[2];
        float ux = 1.0f - wx, uy = 1.0f - wy, uz = 1.0f - wz;
        int zy00 = (z0 * SS + y0) * SS, zy01 = (z0 * SS + y1) * SS;
        int zy10 = (z1 * SS + y0) * SS, zy11 = (z1 * SS + y1) * SS;
        fixs[tid] = uz*uy*ux * f0t[(zy00 + x0) * CC + tid]
                  + uz*uy*wx * f0t[(zy00 + x1) * CC + tid]
                  + uz*wy*ux * f0t[(zy01 + x0) * CC + tid]
                  + uz*wy*wx * f0t[(zy01 + x1) * CC + tid]
                  + wz*uy*ux * f0t[(zy10 + x0) * CC + tid]
                  + wz*uy*wx * f0t[(zy10 + x1) * CC + tid]
                  + wz*wy*ux * f0t[(zy11 + x0) * CC + tid]
                  + wz*wy*wx * f0t[(zy11 + x1) * CC + tid];
    }
    for (int d = tid; d < DD3; d += 256) accb[d] = 0.0f;
    __syncthreads();

    int xb = baseS[0], yb = baseS[1], zb = baseS[2];

    // per-thread gather constants: thread owns (jx,jy), loops jz
    int o00 = 0, o01 = 0, o10 = 0, o11 = 0;
    float w00 = 0.f, w01 = 0.f, w10 = 0.f, w11 = 0.f;
    if (tid < 225) {
        int jx = tid % 15, jy = tid / 15;
        int x0 = l0s[0][jx], x1 = l1s[0][jx]; float wx = wts[0][jx];
        int y0 = l0s[1][jy], y1 = l1s[1][jy]; float wy = wts[1][jy];
        o00 = y0 * WW + x0; o01 = y0 * WW + x1;
        o10 = y1 * WW + x0; o11 = y1 * WW + x1;
        float ux = 1.0f - wx, uy = 1.0f - wy;
        w00 = uy * ux; w01 = uy * wx; w10 = wy * ux; w11 = wy * wx;
    }

    const float2* f5f2 = (const float2*)f5t;

    for (int cg8 = 0; cg8 < 8; ++cg8) {
        // ---- stage window for this channel pair (coalesced rows of 160B) ----
        const float2* src = f5f2 + (size_t)cg8 * NVOX;
        for (int t = tid; t < WIN; t += 256) {
            int lx = t % WW; int r = t / WW; int ly = r % WW; int lz = r / WW;
            int v = ((zb + lz) * SS + (yb + ly)) * SS + (xb + lx);
            win[t] = src[v];
        }
        __syncthreads();

        if (tid < 225) {
            float fxv = fixs[2 * cg8], fyv = fixs[2 * cg8 + 1];
            auto bilin = [&](int lz) -> float2 {
                const float2* pl = win + lz * (WW * WW);
                float2 a = pl[o00], b = pl[o01], c = pl[o10], d4 = pl[o11];
                float2 r;
                r.x = w00 * a.x + w01 * b.x + w10 * c.x + w11 * d4.x;
                r.y = w00 * a.y + w01 * b.y + w10 * c.y + w11 * d4.y;
                return r;
            };
            float2 pA = make_float2(0.f, 0.f), pB = make_float2(0.f, 0.f);
            int zc = -100;
            #pragma unroll 1
            for (int jz = 0; jz < 15; ++jz) {
                int z0 = l0s[2][jz], z1 = l1s[2][jz];   // z0 monotone non-decreasing
                float wz = wts[2][jz];
                if (z0 == zc) {
                    // reuse both cached planes
                } else if (z0 == zc + 1) {
                    pA = pB;
                    pB = (z1 == z0) ? pA : bilin(z1);
                } else {
                    pA = bilin(z0);
                    pB = (z1 == z0) ? pA : bilin(z1);
                }
                zc = z0;
                float uz = 1.0f - wz;
                float mx = uz * pA.x + wz * pB.x;
                float my = uz * pA.y + wz * pB.y;
                float dx_ = fxv - mx, dy_ = fyv - my;
                accb[jz * 225 + tid] += dx_ * dx_ + dy_ * dy_;
            }
        }
        __syncthreads();
    }

    float a0 = alpha[0], a1 = alpha[1];
    float* dcrow = dc + (size_t)g * DD3;
    for (int d = tid; d < DD3; d += 256) dcrow[d] = a1 + a0 * accb[d];
}

// ------------- shared minavg_disp: B[0..3374] holds the input row -------------
// pad_rep(3) -> min3 -> avg3 -> avg3, fully separable. Ping-pong A(8379)/B(7581).
__device__ __forceinline__ void minavg_from_B(float* Abuf, float* Bbuf,
                                              float* outrow, int tid) {
    const float W0 = 1.0f/9.0f, W1 = 2.0f/9.0f, W2 = 3.0f/9.0f;
    __syncthreads();
    // Mz: A[19][21][21], reading B with clamped (replicate-pad) indices
    for (int idx = tid; idx < 19*21*21; idx += 256) {
        int xi = idx % 21; int r = idx / 21; int yi = r % 21; int zi = r / 21;
        int sx = clampi(xi - 3, 0, 14);
        int sy = clampi(yi - 3, 0, 14);
        int z0 = clampi(zi - 3, 0, 14), z1 = clampi(zi - 2, 0, 14), z2 = clampi(zi - 1, 0, 14);
        int o = sy * 15 + sx;
        Abuf[idx] = fminf(fminf(Bbuf[z0*225 + o], Bbuf[z1*225 + o]), Bbuf[z2*225 + o]);
    }
    __syncthreads();
    // My: B[19][19][21]
    for (int idx = tid; idx < 19*19*21; idx += 256) {
        int xi = idx % 21; int r = idx / 21; int yi = r % 19; int zi = r / 19;
        int b = (zi*21 + yi)*21 + xi;
        Bbuf[idx] = fminf(fminf(Abuf[b], Abuf[b+21]), Abuf[b+42]);
    }
    __syncthreads();
    // Mx: A[19][19][19]
    for (int idx = tid; idx < 19*19*19; idx += 256) {
        int xi = idx % 19; int r = idx / 19; int yi = r % 19; int zi = r / 19;
        int b = (zi*19 + yi)*21 + xi;
        Abuf[idx] = fminf(fminf(Bbuf[b], Bbuf[b+1]), Bbuf[b+2]);
    }
    __syncthreads();
    // Cz: B[15][19][19]   (conv [1,2,3,2,1]/9 along z)
    for (int idx = tid; idx < 15*19*19; idx += 256) {
        int xi = idx % 19; int r = idx / 19; int yi = r % 19; int zi = r / 19;
        int b = (zi*19 + yi)*19 + xi;
        Bbuf[idx] = W0*(Abuf[b] + Abuf[b + 4*361]) + W1*(Abuf[b + 361] + Abuf[b + 3*361])
                  + W2*Abuf[b + 2*361];
    }
    __syncthreads();
    // Cy: A[15][15][19]
    for (int idx = tid; idx < 15*15*19; idx += 256) {
        int xi = idx % 19; int r = idx / 19; int yi = r % 15; int zi = r / 15;
        int b = (zi*19 + yi)*19 + xi;
        Abuf[idx] = W0*(Bbuf[b] + Bbuf[b + 4*19]) + W1*(Bbuf[b + 19] + Bbuf[b + 3*19])
                  + W2*Bbuf[b + 2*19];
    }
    __syncthreads();
    // Cx: write 15^3 row to global
    for (int idx = tid; idx < DD3; idx += 256) {
        int xi = idx % 15; int r = idx / 15; int yi = r % 15; int zi = r / 15;
        int b = (zi*15 + yi)*19 + xi;
        outrow[idx] = W0*(Abuf[b] + Abuf[b+4]) + W1*(Abuf[b+1] + Abuf[b+3]) + W2*Abuf[b+2];
    }
}

// ---------------- K2: minavg_disp of dc -> c ----------------
__global__ void __launch_bounds__(256) k_minavg(const float* __restrict__ in, float* out) {
    __shared__ float Abuf[19*21*21];
    __shared__ float Bbuf[19*19*21];
    int tid = threadIdx.x;
    size_t base = (size_t)blockIdx.x * DD3;
    for (int d = tid; d < DD3; d += 256) Bbuf[d] = in[base + d];
    minavg_from_B(Abuf, Bbuf, out + base, tid);
}

// ---------------- grid-axis 1D conv [1,2,3,2,1]/9 with clamp (in-place safe) ----------------
__global__ void __launch_bounds__(256) k_conv_grid(const float* in, float* out, int axis) {
    const float W0 = 1.0f/9.0f, W1 = 2.0f/9.0f, W2 = 3.0f/9.0f;
    int d = blockIdx.x * 256 + threadIdx.x;
    if (d >= DD3) return;
    int line = blockIdx.y;   // 0..840
    size_t base, step;
    if (axis == 0) { base = (size_t)line * GG * DD3; step = DD3; }
    else           { int gz = line / GG, gx = line % GG;
                     base = ((size_t)gz * GG2 + gx) * DD3; step = (size_t)GG * DD3; }
    base += (size_t)d;
    float v[GG];
    #pragma unroll
    for (int i = 0; i < GG; ++i) v[i] = in[base + (size_t)i * step];
    #pragma unroll
    for (int i = 0; i < GG; ++i) {
        int im2 = i-2 < 0 ? 0 : i-2, im1 = i-1 < 0 ? 0 : i-1;
        int ip2 = i+2 > 28 ? 28 : i+2, ip1 = i+1 > 28 ? 28 : i+1;
        out[base + (size_t)i * step] = W0*(v[im2] + v[ip2]) + W1*(v[im1] + v[ip1]) + W2*v[i];
    }
}

// ---------------- K4: z-conv of t2 + combine with dc + minavg_disp -> c3 (row-in-place on dc buffer) ----------------
__global__ void __launch_bounds__(256) k_zcomb_minavg(const float* __restrict__ t2,
                                                      const float* dcin,
                                                      const float* __restrict__ alpha,
                                                      float* c3out) {
    __shared__ float Abuf[19*21*21];
    __shared__ float Bbuf[19*19*21];
    const float W0 = 1.0f/9.0f, W1 = 2.0f/9.0f, W2 = 3.0f/9.0f;
    int tid = threadIdx.x;
    int g = blockIdx.x;
    int gx = g % GG; int gy = (g / GG) % GG; int gz = g / GG2;
    float a2 = alpha[2], a3 = alpha[3], a4 = alpha[4];
    size_t rb0 = ((size_t)((clampi(gz-2,0,28)*GG + gy)*GG + gx)) * DD3;
    size_t rb1 = ((size_t)((clampi(gz-1,0,28)*GG + gy)*GG + gx)) * DD3;
    size_t rb2 = ((size_t)((gz*GG + gy)*GG + gx)) * DD3;
    size_t rb3 = ((size_t)((clampi(gz+1,0,28)*GG + gy)*GG + gx)) * DD3;
    size_t rb4 = ((size_t)((clampi(gz+2,0,28)*GG + gy)*GG + gx)) * DD3;
    const float* drow = dcin + (size_t)g * DD3;
    for (int d = tid; d < DD3; d += 256) {
        float ca = W0*(t2[rb0+d] + t2[rb4+d]) + W1*(t2[rb1+d] + t2[rb3+d]) + W2*t2[rb2+d];
        Bbuf[d] = a4 + a2 * drow[d] + a3 * ca;
    }
    minavg_from_B(Abuf, Bbuf, c3out + (size_t)g * DD3, tid);
}

// ---------------- K7: z-conv of t4 -> softmax -> cost_soft + pred_xyz ----------------
__global__ void __launch_bounds__(256) k_zsoftmax(const float* __restrict__ t4,
                                                  const float* __restrict__ alpha,
                                                  float* __restrict__ cost,
                                                  float* __restrict__ pred) {
    __shared__ float row[DD3];
    __shared__ float4 red4[256];
    const float W0 = 1.0f/9.0f, W1 = 2.0f/9.0f, W2 = 3.0f/9.0f;
    int tid = threadIdx.x;
    int g = blockIdx.x;
    int gx = g % GG; int gy = (g / GG) % GG; int gz = g / GG2;
    float a5 = alpha[5];
    size_t rb0 = ((size_t)((clampi(gz-2,0,28)*GG + gy)*GG + gx)) * DD3;
    size_t rb1 = ((size_t)((clampi(gz-1,0,28)*GG + gy)*GG + gx)) * DD3;
    size_t rb2 = ((size_t)((gz*GG + gy)*GG + gx)) * DD3;
    size_t rb3 = ((size_t)((clampi(gz+1,0,28)*GG + gy)*GG + gx)) * DD3;
    size_t rb4 = ((size_t)((clampi(gz+2,0,28)*GG + gy)*GG + gx)) * DD3;

    float lmax = -3.0e38f;
    for (int d = tid; d < DD3; d += 256) {
        float ca = W0*(t4[rb0+d] + t4[rb4+d]) + W1*(t4[rb1+d] + t4[rb3+d]) + W2*t4[rb2+d];
        float v = -a5 * ca;
        row[d] = v;
        lmax = fmaxf(lmax, v);
    }
    red4[tid].x = lmax;
    __syncthreads();
    for (int s = 128; s > 0; s >>= 1) {
        if (tid < s) red4[tid].x = fmaxf(red4[tid].x, red4[tid + s].x);
        __syncthreads();
    }
    float m = red4[0].x;
    __syncthreads();

    float s0 = 0.f, s1 = 0.f, s2 = 0.f, s3 = 0.f;
    for (int d = tid; d < DD3; d += 256) {
        float p = expf(row[d] - m);
        row[d] = p;
        int jx = d % 15; int r = d / 15; int jy = r % 15; int jz = r / 15;
        s0 += p;
        s1 += p * (0.4f * ((2.0f * jx + 1.0f) / 15.0f - 1.0f));
        s2 += p * (0.4f * ((2.0f * jy + 1.0f) / 15.0f - 1.0f));
        s3 += p * (0.4f * ((2.0f * jz + 1.0f) / 15.0f - 1.0f));
    }
    red4[tid] = make_float4(s0, s1, s2, s3);
    __syncthreads();
    for (int s = 128; s > 0; s >>= 1) {
        if (tid < s) {
            float4 a = red4[tid], b = red4[tid + s];
            red4[tid] = make_float4(a.x + b.x, a.y + b.y, a.z + b.z, a.w + b.w);
        }
        __syncthreads();
    }
    float4 tot = red4[0];
    float inv = 1.0f / tot.x;
    size_t base = (size_t)g * DD3;
    for (int d = tid; d < DD3; d += 256) cost[base + d] = row[d] * inv;
    if (tid == 0) {
        pred[g*3 + 0] = tot.y * inv;
        pred[g*3 + 1] = tot.z * inv;
        pred[g*3 + 2] = tot.w * inv;
    }
}

extern "C" void kernel_launch(void* const* d_in, const int* in_sizes, int n_in,
                              void* d_out, int out_size, void* d_ws, size_t ws_size,
                              hipStream_t stream) {
    const float* feat00 = (const float*)d_in[0];
    const float* feat50 = (const float*)d_in[1];
    const float* alpha  = (const float*)d_in[2];
    float* out = (float*)d_out;
    float* ws  = (float*)d_ws;

    float* ft5  = ws;                            // [8][NVOX] float2  (same bytes as FT_ELEMS floats)
    float* ft0  = ws + FT_ELEMS;                 // [NVOX][16] float
    float* S0   = ws + 2 * FT_ELEMS;             // dc -> c3 -> t4 (row-local reuse)
    float* DOUT = out;                           // scratch use of output buffer: c -> t2
    float* pred = out + (size_t)GG3 * DD3;

    size_t need = ((size_t)2 * FT_ELEMS + (size_t)GG3 * DD3) * sizeof(float);
    if (ws_size < need) return;  // fail cleanly if workspace too small

    // moving image: voxel-major channel-pair layout for LDS window staging
    k_transpose2<<<dim3(NVOX / 256, 8), 256, 0, stream>>>(feat50, ft5);
    // fixed image: voxel-major [v][16] for the per-grid-point fix sample
    k_transpose<<<FT_ELEMS / 256, 256, 0, stream>>>(feat00, ft0);

    // dc (LDS-window gather version)
    k_cost2<<<GG3, 256, 0, stream>>>(ft5, ft0, alpha, S0);
    // c = minavg_disp(dc)
    k_minavg<<<GG3, 256, 0, stream>>>(S0, DOUT);
    // avg_grid x,y on c (in-place; z-conv folded into next kernel)
    dim3 cgrid((DD3 + 255) / 256, GG2);
    k_conv_grid<<<cgrid, 256, 0, stream>>>(DOUT, DOUT, 0);
    k_conv_grid<<<cgrid, 256, 0, stream>>>(DOUT, DOUT, 1);
    // c3 = minavg_disp(a4 + a2*dc + a3*zconv(t2))   (writes over dc buffer, row-local)
    k_zcomb_minavg<<<GG3, 256, 0, stream>>>(DOUT, S0, alpha, S0);
    // avg_grid x,y on c3 (in-place)
    k_conv_grid<<<cgrid, 256, 0, stream>>>(S0, S0, 0);
    k_conv_grid<<<cgrid, 256, 0, stream>>>(S0, S0, 1);
    // z-conv + softmax + pred
    k_zsoftmax<<<GG3, 256, 0, stream>>>(S0, alpha, out, pred);
}

// Round 2
// 4830.105 us; speedup vs baseline: 1.3755x; 1.3572x over previous
//
#include <hip/hip_runtime.h>
#include <cstdint>

#define GG   29
#define GG2  841
#define GG3  24389
#define DD   15
#define DD3  3375
#define SS   48
#define CC   16
#define NVOX (SS*SS*SS)        // 110592
#define FT_ELEMS (NVOX*CC)     // 1769472
#define WXY  20                // window width in x,y
#define WZP  12                // window planes in z (per z-half)
#define WELE (WXY*WXY*WZP)     // 4800 float2 elements

__device__ __forceinline__ int clampi(int v, int lo, int hi) {
    return min(max(v, lo), hi);
}

// ---------------- transpose [C,S,S,S] -> [8 groups][S^3][2ch] (moving image, f2 gather layout) ----
__global__ void __launch_bounds__(256) k_transpose2(const float* __restrict__ f,
                                                    float* __restrict__ ft) {
    int v = blockIdx.x * 256 + threadIdx.x;      // < NVOX (grid sized exactly)
    int cg8 = blockIdx.y;                        // 0..7
    float a = f[(2 * cg8)     * NVOX + v];
    float b = f[(2 * cg8 + 1) * NVOX + v];
    float2* o = (float2*)ft;
    o[(size_t)cg8 * NVOX + v] = make_float2(a, b);
}

// ---------------- K1: deeds cost volume, z-split LDS window, register acc ----------------
// block = one grid point. Thread (jx,jy) = tid<225, jz unrolled with register
// accumulators and z-plane-cached bilinears. Window: 12 z-planes x 20 x 20
// float2 (2 channels) = 38.4 KB -> 4 blocks/CU. 8 channel passes per z-half.
template<int JZ0, int NJZ>
__device__ __forceinline__ void cost_half(const float2* __restrict__ f5f2,
                                          float2* win, const float* fixs,
                                          int tid, int gz, int xb, int yb,
                                          int orel, float wx, float wy,
                                          bool active, float (&acc)[15]) {
    // z tables (block-uniform, computed redundantly per thread; closed-form p)
    float pzb = 24.0f * (float)(2 * gz + 1) / 29.0f - 9.46f;
    float pz0 = fminf(fmaxf(pzb + 1.28f * (float)JZ0, 0.0f), 47.0f);
    int zb = min((int)floorf(pz0), 36);
    int   z0r[NJZ];
    float wzs[NJZ];
    #pragma unroll
    for (int k = 0; k < NJZ; ++k) {
        float pz = fminf(fmaxf(pzb + 1.28f * (float)(JZ0 + k), 0.0f), 47.0f);
        int z0 = min((int)floorf(pz), 46);
        z0r[k] = z0 - zb;
        wzs[k] = pz - (float)z0;
    }

    // staging addresses: hoisted out of the channel-pass loop (pass-invariant)
    int vox[19];
    #pragma unroll
    for (int k = 0; k < 19; ++k) {
        int idx = tid + (k << 8);
        if (idx < WELE) {
            int lz  = idx / 400;
            int rem = idx - lz * 400;
            int ly  = rem / 20;
            int lx  = rem - ly * 20;
            vox[k] = ((zb + lz) * SS + (yb + ly)) * SS + (xb + lx);
        }
    }

    #pragma unroll 1
    for (int cg8 = 0; cg8 < 8; ++cg8) {
        const float2* src = f5f2 + (size_t)cg8 * NVOX;
        #pragma unroll
        for (int k = 0; k < 19; ++k) {
            int idx = tid + (k << 8);
            if (idx < WELE) win[idx] = src[vox[k]];
        }
        __syncthreads();

        if (active) {
            float fx0 = fixs[2 * cg8], fx1 = fixs[2 * cg8 + 1];
            float2 pA = make_float2(0.f, 0.f), pB = make_float2(0.f, 0.f);
            int zprev = -99;
            #pragma unroll
            for (int k = 0; k < NJZ; ++k) {
                int zr = z0r[k]; float wz = wzs[k];
                if (zr != zprev) {
                    if (zr == zprev + 1) {
                        pA = pB;
                    } else {
                        const float2* P = win + zr * 400 + orel;
                        float2 a = P[0], b = P[1], c = P[20], d = P[21];
                        float bx0x = a.x + wx * (b.x - a.x), bx0y = a.y + wx * (b.y - a.y);
                        float bx1x = c.x + wx * (d.x - c.x), bx1y = c.y + wx * (d.y - c.y);
                        pA = make_float2(bx0x + wy * (bx1x - bx0x), bx0y + wy * (bx1y - bx0y));
                    }
                    const float2* Q = win + (zr + 1) * 400 + orel;
                    float2 a = Q[0], b = Q[1], c = Q[20], d = Q[21];
                    float bx0x = a.x + wx * (b.x - a.x), bx0y = a.y + wx * (b.y - a.y);
                    float bx1x = c.x + wx * (d.x - c.x), bx1y = c.y + wx * (d.y - c.y);
                    pB = make_float2(bx0x + wy * (bx1x - bx0x), bx0y + wy * (bx1y - bx0y));
                    zprev = zr;
                }
                float mx = pA.x + wz * (pB.x - pA.x);
                float my = pA.y + wz * (pB.y - pA.y);
                float dx = fx0 - mx, dy = fx1 - my;
                acc[JZ0 + k] += dx * dx + dy * dy;
            }
        }
        __syncthreads();
    }
}

__global__ void __launch_bounds__(256, 4) k_cost3(const float* __restrict__ f5t,   // float2 [8][NVOX]
                                                  const float* __restrict__ feat00,// [C][NVOX]
                                                  const float* __restrict__ alpha,
                                                  float* __restrict__ dc) {
    __shared__ float2 win[WELE];         // 38.4 KB
    __shared__ float  fixs[16];

    int tid = threadIdx.x;
    int g = blockIdx.x;
    int gx = g % GG; int gy = (g / GG) % GG; int gz = g / GG2;

    // fixed-image feature at the (unshifted) grid point, channel = tid
    if (tid < CC) {
        int giv[3] = {gx, gy, gz};
        int i0[3]; float w[3];
        #pragma unroll
        for (int a = 0; a < 3; ++a) {
            float cgv = (2.0f * giv[a] + 1.0f) / 29.0f - 1.0f;
            float p = ((cgv + 1.0f) * 48.0f - 1.0f) * 0.5f;
            p = fminf(fmaxf(p, 0.0f), 47.0f);
            float fl = floorf(p);
            i0[a] = (int)fl; w[a] = p - fl;
        }
        int x0 = i0[0], y0 = i0[1], z0 = i0[2];
        int x1 = min(x0 + 1, 47), y1 = min(y0 + 1, 47), z1 = min(z0 + 1, 47);
        float wx = w[0], wy = w[1], wz = w[2];
        float ux = 1.0f - wx, uy = 1.0f - wy, uz = 1.0f - wz;
        const float* fc = feat00 + (size_t)tid * NVOX;
        int zy00 = (z0 * SS + y0) * SS, zy01 = (z0 * SS + y1) * SS;
        int zy10 = (z1 * SS + y0) * SS, zy11 = (z1 * SS + y1) * SS;
        fixs[tid] = uz*uy*ux * fc[zy00 + x0] + uz*uy*wx * fc[zy00 + x1]
                  + uz*wy*ux * fc[zy01 + x0] + uz*wy*wx * fc[zy01 + x1]
                  + wz*uy*ux * fc[zy10 + x0] + wz*uy*wx * fc[zy10 + x1]
                  + wz*wy*ux * fc[zy11 + x0] + wz*wy*wx * fc[zy11 + x1];
    }

    // per-thread x/y sample setup (closed-form p = pb + 1.28*j, clamp-continuous)
    float pxb = 24.0f * (float)(2 * gx + 1) / 29.0f - 9.46f;
    float pyb = 24.0f * (float)(2 * gy + 1) / 29.0f - 9.46f;
    int xb = min((int)floorf(fminf(fmaxf(pxb, 0.0f), 47.0f)), SS - WXY);
    int yb = min((int)floorf(fminf(fmaxf(pyb, 0.0f), 47.0f)), SS - WXY);

    bool active = tid < 225;
    int jx = tid % 15, jy = tid / 15;
    float px = fminf(fmaxf(pxb + 1.28f * (float)jx, 0.0f), 47.0f);
    float py = fminf(fmaxf(pyb + 1.28f * (float)jy, 0.0f), 47.0f);
    int x0 = min((int)floorf(px), 46);
    int y0 = min((int)floorf(py), 46);
    float wx = px - (float)x0;
    float wy = py - (float)y0;
    int orel = (y0 - yb) * WXY + (x0 - xb);

    float acc[15];
    #pragma unroll
    for (int k = 0; k < 15; ++k) acc[k] = 0.0f;

    const float2* f5f2 = (const float2*)f5t;
    cost_half<0, 8>(f5f2, win, fixs, tid, gz, xb, yb, orel, wx, wy, active, acc);
    cost_half<8, 7>(f5f2, win, fixs, tid, gz, xb, yb, orel, wx, wy, active, acc);

    float a0 = alpha[0], a1 = alpha[1];
    if (active) {
        float* dcrow = dc + (size_t)g * DD3;
        #pragma unroll
        for (int k = 0; k < 15; ++k) dcrow[k * 225 + tid] = a1 + a0 * acc[k];
    }
}

// ------------- shared minavg_disp: B[0..3374] holds the input row -------------
// pad_rep(3) -> min3 -> avg3 -> avg3, fully separable. Ping-pong A(8379)/B(7581).
__device__ __forceinline__ void minavg_from_B(float* Abuf, float* Bbuf,
                                              float* outrow, int tid) {
    const float W0 = 1.0f/9.0f, W1 = 2.0f/9.0f, W2 = 3.0f/9.0f;
    __syncthreads();
    // Mz: A[19][21][21], reading B with clamped (replicate-pad) indices
    for (int idx = tid; idx < 19*21*21; idx += 256) {
        int xi = idx % 21; int r = idx / 21; int yi = r % 21; int zi = r / 21;
        int sx = clampi(xi - 3, 0, 14);
        int sy = clampi(yi - 3, 0, 14);
        int z0 = clampi(zi - 3, 0, 14), z1 = clampi(zi - 2, 0, 14), z2 = clampi(zi - 1, 0, 14);
        int o = sy * 15 + sx;
        Abuf[idx] = fminf(fminf(Bbuf[z0*225 + o], Bbuf[z1*225 + o]), Bbuf[z2*225 + o]);
    }
    __syncthreads();
    // My: B[19][19][21]
    for (int idx = tid; idx < 19*19*21; idx += 256) {
        int xi = idx % 21; int r = idx / 21; int yi = r % 19; int zi = r / 19;
        int b = (zi*21 + yi)*21 + xi;
        Bbuf[idx] = fminf(fminf(Abuf[b], Abuf[b+21]), Abuf[b+42]);
    }
    __syncthreads();
    // Mx: A[19][19][19]
    for (int idx = tid; idx < 19*19*19; idx += 256) {
        int xi = idx % 19; int r = idx / 19; int yi = r % 19; int zi = r / 19;
        int b = (zi*19 + yi)*21 + xi;
        Abuf[idx] = fminf(fminf(Bbuf[b], Bbuf[b+1]), Bbuf[b+2]);
    }
    __syncthreads();
    // Cz: B[15][19][19]   (conv [1,2,3,2,1]/9 along z)
    for (int idx = tid; idx < 15*19*19; idx += 256) {
        int xi = idx % 19; int r = idx / 19; int yi = r % 19; int zi = r / 19;
        int b = (zi*19 + yi)*19 + xi;
        Bbuf[idx] = W0*(Abuf[b] + Abuf[b + 4*361]) + W1*(Abuf[b + 361] + Abuf[b + 3*361])
                  + W2*Abuf[b + 2*361];
    }
    __syncthreads();
    // Cy: A[15][15][19]
    for (int idx = tid; idx < 15*15*19; idx += 256) {
        int xi = idx % 19; int r = idx / 19; int yi = r % 15; int zi = r / 15;
        int b = (zi*19 + yi)*19 + xi;
        Abuf[idx] = W0*(Bbuf[b] + Bbuf[b + 4*19]) + W1*(Bbuf[b + 19] + Bbuf[b + 3*19])
                  + W2*Bbuf[b + 2*19];
    }
    __syncthreads();
    // Cx: write 15^3 row to global
    for (int idx = tid; idx < DD3; idx += 256) {
        int xi = idx % 15; int r = idx / 15; int yi = r % 15; int zi = r / 15;
        int b = (zi*15 + yi)*19 + xi;
        outrow[idx] = W0*(Abuf[b] + Abuf[b+4]) + W1*(Abuf[b+1] + Abuf[b+3]) + W2*Abuf[b+2];
    }
}

// ---------------- K2: minavg_disp of dc -> c ----------------
__global__ void __launch_bounds__(256) k_minavg(const float* __restrict__ in, float* out) {
    __shared__ float Abuf[19*21*21];
    __shared__ float Bbuf[19*19*21];
    int tid = threadIdx.x;
    size_t base = (size_t)blockIdx.x * DD3;
    for (int d = tid; d < DD3; d += 256) Bbuf[d] = in[base + d];
    minavg_from_B(Abuf, Bbuf, out + base, tid);
}

// ---------------- grid-axis 1D conv [1,2,3,2,1]/9 with clamp (in-place safe) ----------------
__global__ void __launch_bounds__(256) k_conv_grid(const float* in, float* out, int axis) {
    const float W0 = 1.0f/9.0f, W1 = 2.0f/9.0f, W2 = 3.0f/9.0f;
    int d = blockIdx.x * 256 + threadIdx.x;
    if (d >= DD3) return;
    int line = blockIdx.y;   // 0..840
    size_t base, step;
    if (axis == 0) { base = (size_t)line * GG * DD3; step = DD3; }
    else           { int gz = line / GG, gx = line % GG;
                     base = ((size_t)gz * GG2 + gx) * DD3; step = (size_t)GG * DD3; }
    base += (size_t)d;
    float v[GG];
    #pragma unroll
    for (int i = 0; i < GG; ++i) v[i] = in[base + (size_t)i * step];
    #pragma unroll
    for (int i = 0; i < GG; ++i) {
        int im2 = i-2 < 0 ? 0 : i-2, im1 = i-1 < 0 ? 0 : i-1;
        int ip2 = i+2 > 28 ? 28 : i+2, ip1 = i+1 > 28 ? 28 : i+1;
        out[base + (size_t)i * step] = W0*(v[im2] + v[ip2]) + W1*(v[im1] + v[ip1]) + W2*v[i];
    }
}

// ---------------- K4: z-conv of t2 + combine with dc + minavg_disp -> c3 (row-in-place on dc buffer) ----------------
__global__ void __launch_bounds__(256) k_zcomb_minavg(const float* __restrict__ t2,
                                                      const float* dcin,
                                                      const float* __restrict__ alpha,
                                                      float* c3out) {
    __shared__ float Abuf[19*21*21];
    __shared__ float Bbuf[19*19*21];
    const float W0 = 1.0f/9.0f, W1 = 2.0f/9.0f, W2 = 3.0f/9.0f;
    int tid = threadIdx.x;
    int g = blockIdx.x;
    int gx = g % GG; int gy = (g / GG) % GG; int gz = g / GG2;
    float a2 = alpha[2], a3 = alpha[3], a4 = alpha[4];
    size_t rb0 = ((size_t)((clampi(gz-2,0,28)*GG + gy)*GG + gx)) * DD3;
    size_t rb1 = ((size_t)((clampi(gz-1,0,28)*GG + gy)*GG + gx)) * DD3;
    size_t rb2 = ((size_t)((gz*GG + gy)*GG + gx)) * DD3;
    size_t rb3 = ((size_t)((clampi(gz+1,0,28)*GG + gy)*GG + gx)) * DD3;
    size_t rb4 = ((size_t)((clampi(gz+2,0,28)*GG + gy)*GG + gx)) * DD3;
    const float* drow = dcin + (size_t)g * DD3;
    for (int d = tid; d < DD3; d += 256) {
        float ca = W0*(t2[rb0+d] + t2[rb4+d]) + W1*(t2[rb1+d] + t2[rb3+d]) + W2*t2[rb2+d];
        Bbuf[d] = a4 + a2 * drow[d] + a3 * ca;
    }
    minavg_from_B(Abuf, Bbuf, c3out + (size_t)g * DD3, tid);
}

// ---------------- K7: z-conv of t4 -> softmax -> cost_soft + pred_xyz ----------------
__global__ void __launch_bounds__(256) k_zsoftmax(const float* __restrict__ t4,
                                                  const float* __restrict__ alpha,
                                                  float* __restrict__ cost,
                                                  float* __restrict__ pred) {
    __shared__ float row[DD3];
    __shared__ float4 red4[256];
    const float W0 = 1.0f/9.0f, W1 = 2.0f/9.0f, W2 = 3.0f/9.0f;
    int tid = threadIdx.x;
    int g = blockIdx.x;
    int gx = g % GG; int gy = (g / GG) % GG; int gz = g / GG2;
    float a5 = alpha[5];
    size_t rb0 = ((size_t)((clampi(gz-2,0,28)*GG + gy)*GG + gx)) * DD3;
    size_t rb1 = ((size_t)((clampi(gz-1,0,28)*GG + gy)*GG + gx)) * DD3;
    size_t rb2 = ((size_t)((gz*GG + gy)*GG + gx)) * DD3;
    size_t rb3 = ((size_t)((clampi(gz+1,0,28)*GG + gy)*GG + gx)) * DD3;
    size_t rb4 = ((size_t)((clampi(gz+2,0,28)*GG + gy)*GG + gx)) * DD3;

    float lmax = -3.0e38f;
    for (int d = tid; d < DD3; d += 256) {
        float ca = W0*(t4[rb0+d] + t4[rb4+d]) + W1*(t4[rb1+d] + t4[rb3+d]) + W2*t4[rb2+d];
        float v = -a5 * ca;
        row[d] = v;
        lmax = fmaxf(lmax, v);
    }
    red4[tid].x = lmax;
    __syncthreads();
    for (int s = 128; s > 0; s >>= 1) {
        if (tid < s) red4[tid].x = fmaxf(red4[tid].x, red4[tid + s].x);
        __syncthreads();
    }
    float m = red4[0].x;
    __syncthreads();

    float s0 = 0.f, s1 = 0.f, s2 = 0.f, s3 = 0.f;
    for (int d = tid; d < DD3; d += 256) {
        float p = expf(row[d] - m);
        row[d] = p;
        int jx = d % 15; int r = d / 15; int jy = r % 15; int jz = r / 15;
        s0 += p;
        s1 += p * (0.4f * ((2.0f * jx + 1.0f) / 15.0f - 1.0f));
        s2 += p * (0.4f * ((2.0f * jy + 1.0f) / 15.0f - 1.0f));
        s3 += p * (0.4f * ((2.0f * jz + 1.0f) / 15.0f - 1.0f));
    }
    red4[tid] = make_float4(s0, s1, s2, s3);
    __syncthreads();
    for (int s = 128; s > 0; s >>= 1) {
        if (tid < s) {
            float4 a = red4[tid], b = red4[tid + s];
            red4[tid] = make_float4(a.x + b.x, a.y + b.y, a.z + b.z, a.w + b.w);
        }
        __syncthreads();
    }
    float4 tot = red4[0];
    float inv = 1.0f / tot.x;
    size_t base = (size_t)g * DD3;
    for (int d = tid; d < DD3; d += 256) cost[base + d] = row[d] * inv;
    if (tid == 0) {
        pred[g*3 + 0] = tot.y * inv;
        pred[g*3 + 1] = tot.z * inv;
        pred[g*3 + 2] = tot.w * inv;
    }
}

extern "C" void kernel_launch(void* const* d_in, const int* in_sizes, int n_in,
                              void* d_out, int out_size, void* d_ws, size_t ws_size,
                              hipStream_t stream) {
    const float* feat00 = (const float*)d_in[0];
    const float* feat50 = (const float*)d_in[1];
    const float* alpha  = (const float*)d_in[2];
    float* out = (float*)d_out;
    float* ws  = (float*)d_ws;

    float* ft5  = ws;                            // [8][NVOX] float2  (FT_ELEMS floats)
    float* S0   = ws + FT_ELEMS;                 // dc -> c3 -> t4 (row-local reuse)
    float* DOUT = out;                           // scratch use of output buffer: c -> t2
    float* pred = out + (size_t)GG3 * DD3;

    size_t need = ((size_t)FT_ELEMS + (size_t)GG3 * DD3) * sizeof(float);
    if (ws_size < need) return;  // fail cleanly if workspace too small

    // moving image: voxel-major channel-pair layout for LDS window staging
    k_transpose2<<<dim3(NVOX / 256, 8), 256, 0, stream>>>(feat50, ft5);

    // dc (z-split LDS-window, register-accumulator version)
    k_cost3<<<GG3, 256, 0, stream>>>(ft5, feat00, alpha, S0);
    // c = minavg_disp(dc)
    k_minavg<<<GG3, 256, 0, stream>>>(S0, DOUT);
    // avg_grid x,y on c (in-place; z-conv folded into next kernel)
    dim3 cgrid((DD3 + 255) / 256, GG2);
    k_conv_grid<<<cgrid, 256, 0, stream>>>(DOUT, DOUT, 0);
    k_conv_grid<<<cgrid, 256, 0, stream>>>(DOUT, DOUT, 1);
    // c3 = minavg_disp(a4 + a2*dc + a3*zconv(t2))   (writes over dc buffer, row-local)
    k_zcomb_minavg<<<GG3, 256, 0, stream>>>(DOUT, S0, alpha, S0);
    // avg_grid x,y on c3 (in-place)
    k_conv_grid<<<cgrid, 256, 0, stream>>>(S0, S0, 0);
    k_conv_grid<<<cgrid, 256, 0, stream>>>(S0, S0, 1);
    // z-conv + softmax + pred
    k_zsoftmax<<<GG3, 256, 0, stream>>>(S0, alpha, out, pred);
}

// Round 3
// 2812.450 us; speedup vs baseline: 2.3623x; 1.7174x over previous
//
#include <hip/hip_runtime.h>
#include <cstdint>

#define GG   29
#define GG2  841
#define GG3  24389
#define DD   15
#define DD3  3375
#define SS   48
#define CC   16
#define NVOX (SS*SS*SS)        // 110592
#define FT_ELEMS (NVOX*CC)     // 1769472
#define WXY  20                // window width in x,y
#define WZC  6                 // window planes per z-chunk
#define WELE4 (WXY*WXY*WZC)    // 2400 float4

#define MW0 (1.0f/9.0f)
#define MW1 (2.0f/9.0f)
#define MW2 (3.0f/9.0f)

__device__ __forceinline__ int clampi(int v, int lo, int hi) {
    return min(max(v, lo), hi);
}

__device__ __forceinline__ float4 f4min3(float4 a, float4 b, float4 c) {
    return make_float4(fminf(fminf(a.x,b.x),c.x), fminf(fminf(a.y,b.y),c.y),
                       fminf(fminf(a.z,b.z),c.z), fminf(fminf(a.w,b.w),c.w));
}
__device__ __forceinline__ void f4acc(float4& o, float w, float4 a) {
    o.x += w*a.x; o.y += w*a.y; o.z += w*a.z; o.w += w*a.w;
}

// ---------------- transpose [C,S,S,S] -> [4 groups][S^3] float4 (moving image) ----------------
__global__ void __launch_bounds__(256) k_transpose4(const float* __restrict__ f,
                                                    float* __restrict__ ft) {
    int v = blockIdx.x * 256 + threadIdx.x;      // < NVOX (grid sized exactly)
    int cg4 = blockIdx.y;                        // 0..3
    float4 o = make_float4(f[(4*cg4+0)*NVOX + v], f[(4*cg4+1)*NVOX + v],
                           f[(4*cg4+2)*NVOX + v], f[(4*cg4+3)*NVOX + v]);
    ((float4*)ft)[(size_t)cg4 * NVOX + v] = o;
}

// ---------------- K1: deeds cost volume, float4 channel-quads, 6-plane z-chunks ----------------
template<int JZ0, int NJZ>
__device__ __forceinline__ void cost_chunk(const float4* __restrict__ f5f4,
                                           float4* win, const float4* fixs4,
                                           int tid, float pzb, int xb, int yb,
                                           int orel, float wx, float wy,
                                           bool active, float (&acc)[15]) {
    float pz0 = fminf(fmaxf(pzb + 1.28f * (float)JZ0, 0.0f), 47.0f);
    int zb = min((int)floorf(pz0), SS - WZC);   // <= 42
    int   z0r[NJZ];
    float wzs[NJZ];
    #pragma unroll
    for (int k = 0; k < NJZ; ++k) {
        float pz = fminf(fmaxf(pzb + 1.28f * (float)(JZ0 + k), 0.0f), 47.0f);
        int z0 = min((int)floorf(pz), 46);
        z0r[k] = z0 - zb;          // in [0,4]
        wzs[k] = pz - (float)z0;
    }

    // staging addresses hoisted across channel passes
    int vox[10];
    #pragma unroll
    for (int k = 0; k < 10; ++k) {
        int idx = tid + (k << 8);
        if (idx < WELE4) {
            int lz  = idx / 400;
            int rem = idx - lz * 400;
            int ly  = rem / 20;
            int lx  = rem - ly * 20;
            vox[k] = ((zb + lz) * SS + (yb + ly)) * SS + (xb + lx);
        }
    }

    auto bilin = [&](int zr) -> float4 {
        const float4* P = win + zr * 400 + orel;
        float4 a = P[0], b = P[1], c = P[20], d = P[21];
        float r0x = a.x + wx*(b.x-a.x), r0y = a.y + wx*(b.y-a.y);
        float r0z = a.z + wx*(b.z-a.z), r0w = a.w + wx*(b.w-a.w);
        float r1x = c.x + wx*(d.x-c.x), r1y = c.y + wx*(d.y-c.y);
        float r1z = c.z + wx*(d.z-c.z), r1w = c.w + wx*(d.w-c.w);
        return make_float4(r0x + wy*(r1x-r0x), r0y + wy*(r1y-r0y),
                           r0z + wy*(r1z-r0z), r0w + wy*(r1w-r0w));
    };

    #pragma unroll 1
    for (int cg4 = 0; cg4 < 4; ++cg4) {
        const float4* src = f5f4 + (size_t)cg4 * NVOX;
        #pragma unroll
        for (int k = 0; k < 10; ++k) {
            int idx = tid + (k << 8);
            if (idx < WELE4) win[idx] = src[vox[k]];
        }
        __syncthreads();

        if (active) {
            float4 fx = fixs4[cg4];
            float4 pA = make_float4(0.f,0.f,0.f,0.f), pB = pA;
            int zprev = -99;
            #pragma unroll
            for (int k = 0; k < NJZ; ++k) {
                int zr = z0r[k]; float wz = wzs[k];
                if (zr != zprev) {
                    if (zr == zprev + 1) pA = pB;
                    else                 pA = bilin(zr);
                    pB = bilin(zr + 1);
                    zprev = zr;
                }
                float mx = pA.x + wz*(pB.x-pA.x);
                float my = pA.y + wz*(pB.y-pA.y);
                float mz = pA.z + wz*(pB.z-pA.z);
                float mw = pA.w + wz*(pB.w-pA.w);
                float dx = fx.x - mx, dy = fx.y - my, dz = fx.z - mz, dw = fx.w - mw;
                acc[JZ0 + k] += dx*dx + dy*dy + dz*dz + dw*dw;
            }
        }
        __syncthreads();
    }
}

__global__ void __launch_bounds__(256, 4) k_cost4(const float* __restrict__ f5t,   // float4 [4][NVOX]
                                                  const float* __restrict__ feat00,// [C][NVOX]
                                                  const float* __restrict__ alpha,
                                                  float* __restrict__ dc) {
    __shared__ float4 win[WELE4];        // 38.4 KB
    __shared__ float4 fixs4[4];

    int tid = threadIdx.x;
    int g = blockIdx.x;
    int gx = g % GG; int gy = (g / GG) % GG; int gz = g / GG2;

    if (tid < CC) {
        int giv[3] = {gx, gy, gz};
        int i0[3]; float w[3];
        #pragma unroll
        for (int a = 0; a < 3; ++a) {
            float cgv = (2.0f * giv[a] + 1.0f) / 29.0f - 1.0f;
            float p = ((cgv + 1.0f) * 48.0f - 1.0f) * 0.5f;
            p = fminf(fmaxf(p, 0.0f), 47.0f);
            float fl = floorf(p);
            i0[a] = (int)fl; w[a] = p - fl;
        }
        int x0 = i0[0], y0 = i0[1], z0 = i0[2];
        int x1 = min(x0 + 1, 47), y1 = min(y0 + 1, 47), z1 = min(z0 + 1, 47);
        float wx = w[0], wy = w[1], wz = w[2];
        float ux = 1.0f - wx, uy = 1.0f - wy, uz = 1.0f - wz;
        const float* fc = feat00 + (size_t)tid * NVOX;
        int zy00 = (z0 * SS + y0) * SS, zy01 = (z0 * SS + y1) * SS;
        int zy10 = (z1 * SS + y0) * SS, zy11 = (z1 * SS + y1) * SS;
        ((float*)fixs4)[tid] =
              uz*uy*ux * fc[zy00 + x0] + uz*uy*wx * fc[zy00 + x1]
            + uz*wy*ux * fc[zy01 + x0] + uz*wy*wx * fc[zy01 + x1]
            + wz*uy*ux * fc[zy10 + x0] + wz*uy*wx * fc[zy10 + x1]
            + wz*wy*ux * fc[zy11 + x0] + wz*wy*wx * fc[zy11 + x1];
    }

    float pxb = 24.0f * (float)(2 * gx + 1) / 29.0f - 9.46f;
    float pyb = 24.0f * (float)(2 * gy + 1) / 29.0f - 9.46f;
    float pzb = 24.0f * (float)(2 * gz + 1) / 29.0f - 9.46f;
    int xb = min((int)floorf(fminf(fmaxf(pxb, 0.0f), 47.0f)), SS - WXY);
    int yb = min((int)floorf(fminf(fmaxf(pyb, 0.0f), 47.0f)), SS - WXY);

    bool active = tid < 225;
    int jx = tid % 15, jy = tid / 15;
    float px = fminf(fmaxf(pxb + 1.28f * (float)jx, 0.0f), 47.0f);
    float py = fminf(fmaxf(pyb + 1.28f * (float)jy, 0.0f), 47.0f);
    int x0 = min((int)floorf(px), 46);
    int y0 = min((int)floorf(py), 46);
    float wx = px - (float)x0;
    float wy = py - (float)y0;
    int orel = (y0 - yb) * WXY + (x0 - xb);

    float acc[15];
    #pragma unroll
    for (int k = 0; k < 15; ++k) acc[k] = 0.0f;

    const float4* f5f4 = (const float4*)f5t;
    cost_chunk<0, 4>(f5f4, win, fixs4, tid, pzb, xb, yb, orel, wx, wy, active, acc);
    cost_chunk<4, 4>(f5f4, win, fixs4, tid, pzb, xb, yb, orel, wx, wy, active, acc);
    cost_chunk<8, 4>(f5f4, win, fixs4, tid, pzb, xb, yb, orel, wx, wy, active, acc);
    cost_chunk<12,3>(f5f4, win, fixs4, tid, pzb, xb, yb, orel, wx, wy, active, acc);

    float a0 = alpha[0], a1 = alpha[1];
    if (active) {
        float* dcrow = dc + (size_t)g * DD3;
        #pragma unroll
        for (int k = 0; k < 15; ++k) dcrow[k * 225 + tid] = a1 + a0 * acc[k];
    }
}

// ------------- minavg_disp, z-column register version -------------
// Input: v[15] = this thread's (x,y) z-column (tid<225). All LDS traffic is
// aligned float4 column vectors; sliding min / 5-tap conv done in registers.
// U >= 5776 floats, V >= 5700 floats.
__device__ __forceinline__ void minavg_cols(float* U, float* V, float (&v)[15],
                                            int tid, float* __restrict__ outrow) {
    // P1: z-min (pad-replicate) 15 -> 19 (slot 19 dup for vector fill)
    if (tid < 225) {
        float m[20];
        #pragma unroll
        for (int zi = 0; zi < 20; ++zi)
            m[zi] = fminf(fminf(v[clampi(zi-3,0,14)], v[clampi(zi-2,0,14)]),
                          v[clampi(zi-1,0,14)]);
        float4* u4 = (float4*)&U[tid*20];
        const float4* m4 = (const float4*)m;
        #pragma unroll
        for (int q = 0; q < 5; ++q) u4[q] = m4[q];
    }
    __syncthreads();
    // P2: y-min (pad-replicate): out cols (sx in 15, yi in 19) = 285
    for (int c = tid; c < 285; c += 256) {
        int sx = c % 15, yi = c / 15;
        const float4* A = (const float4*)&U[(clampi(yi-3,0,14)*15 + sx)*20];
        const float4* B = (const float4*)&U[(clampi(yi-2,0,14)*15 + sx)*20];
        const float4* Cc= (const float4*)&U[(clampi(yi-1,0,14)*15 + sx)*20];
        float4* vv = (float4*)&V[c*20];
        #pragma unroll
        for (int q = 0; q < 5; ++q) vv[q] = f4min3(A[q], B[q], Cc[q]);
    }
    __syncthreads();
    // P3: x-min (pad-replicate) + z-conv: out cols (xi in 19, yi in 19) = 361
    for (int c = tid; c < 361; c += 256) {
        int xi = c % 19, yi = c / 19;
        int s0 = clampi(xi-3,0,14), s1 = clampi(xi-2,0,14), s2 = clampi(xi-1,0,14);
        const float4* A = (const float4*)&V[(yi*15 + s0)*20];
        const float4* B = (const float4*)&V[(yi*15 + s1)*20];
        const float4* Cc= (const float4*)&V[(yi*15 + s2)*20];
        float m[20];
        float4* m4 = (float4*)m;
        #pragma unroll
        for (int q = 0; q < 5; ++q) m4[q] = f4min3(A[q], B[q], Cc[q]);
        float cz[16];
        #pragma unroll
        for (int zi = 0; zi < 15; ++zi)
            cz[zi] = MW0*(m[zi] + m[zi+4]) + MW1*(m[zi+1] + m[zi+3]) + MW2*m[zi+2];
        cz[15] = cz[14];
        float4* u4 = (float4*)&U[c*16];
        const float4* c4 = (const float4*)cz;
        #pragma unroll
        for (int q = 0; q < 4; ++q) u4[q] = c4[q];
    }
    __syncthreads();
    // P4: y-conv (interior 5-tap): out cols (xi in 19, yi in 15) = 285
    for (int c = tid; c < 285; c += 256) {
        int xi = c % 19, yi = c / 19;
        float4 o0 = make_float4(0.f,0.f,0.f,0.f), o1 = o0, o2 = o0, o3 = o0;
        const float W[5] = {MW0, MW1, MW2, MW1, MW0};
        #pragma unroll
        for (int t = 0; t < 5; ++t) {
            const float4* A = (const float4*)&U[((yi+t)*19 + xi)*16];
            float w = W[t];
            f4acc(o0, w, A[0]); f4acc(o1, w, A[1]);
            f4acc(o2, w, A[2]); f4acc(o3, w, A[3]);
        }
        float4* vv = (float4*)&V[c*16];
        vv[0] = o0; vv[1] = o1; vv[2] = o2; vv[3] = o3;
    }
    __syncthreads();
    // P5: x-conv (interior 5-tap): out cols (xi in 15, yi in 15) = 225
    if (tid < 225) {
        int xi = tid % 15, yi = tid / 15;
        float4 o0 = make_float4(0.f,0.f,0.f,0.f), o1 = o0, o2 = o0, o3 = o0;
        const float W[5] = {MW0, MW1, MW2, MW1, MW0};
        #pragma unroll
        for (int t = 0; t < 5; ++t) {
            const float4* A = (const float4*)&V[(yi*19 + xi + t)*16];
            float w = W[t];
            f4acc(o0, w, A[0]); f4acc(o1, w, A[1]);
            f4acc(o2, w, A[2]); f4acc(o3, w, A[3]);
        }
        float4* u4 = (float4*)&U[tid*16];
        u4[0] = o0; u4[1] = o1; u4[2] = o2; u4[3] = o3;
    }
    __syncthreads();
    // P6: transpose back to z-major layout, coalesced global write
    for (int d = tid; d < DD3; d += 256)
        outrow[d] = U[(d % 225)*16 + d/225];
}

// ---------------- K2: minavg_disp of dc -> c ----------------
__global__ void __launch_bounds__(256) k_minavg2(const float* __restrict__ in, float* out) {
    __shared__ __align__(16) float U[5776];
    __shared__ __align__(16) float V[5700];
    int tid = threadIdx.x;
    size_t base = (size_t)blockIdx.x * DD3;
    float v[15];
    if (tid < 225) {
        #pragma unroll
        for (int z = 0; z < 15; ++z) v[z] = in[base + z*225 + tid];
    }
    minavg_cols(U, V, v, tid, out + base);
}

// ---------------- grid-axis 1D conv [1,2,3,2,1]/9 with clamp (in-place safe) ----------------
__global__ void __launch_bounds__(256) k_conv_grid(const float* in, float* out, int axis) {
    int d = blockIdx.x * 256 + threadIdx.x;
    if (d >= DD3) return;
    int line = blockIdx.y;   // 0..840
    size_t base, step;
    if (axis == 0) { base = (size_t)line * GG * DD3; step = DD3; }
    else           { int gz = line / GG, gx = line % GG;
                     base = ((size_t)gz * GG2 + gx) * DD3; step = (size_t)GG * DD3; }
    base += (size_t)d;
    float v[GG];
    #pragma unroll
    for (int i = 0; i < GG; ++i) v[i] = in[base + (size_t)i * step];
    #pragma unroll
    for (int i = 0; i < GG; ++i) {
        int im2 = i-2 < 0 ? 0 : i-2, im1 = i-1 < 0 ? 0 : i-1;
        int ip2 = i+2 > 28 ? 28 : i+2, ip1 = i+1 > 28 ? 28 : i+1;
        out[base + (size_t)i * step] = MW0*(v[im2] + v[ip2]) + MW1*(v[im1] + v[ip1]) + MW2*v[i];
    }
}

// ---------------- K4: z-conv of t2 + combine with dc + minavg_disp -> c3 ----------------
__global__ void __launch_bounds__(256) k_zcomb2(const float* __restrict__ t2,
                                                const float* __restrict__ dcin,
                                                const float* __restrict__ alpha,
                                                float* c3out) {
    __shared__ __align__(16) float U[5776];
    __shared__ __align__(16) float V[5700];
    int tid = threadIdx.x;
    int g = blockIdx.x;
    int gx = g % GG; int gy = (g / GG) % GG; int gz = g / GG2;
    float a2 = alpha[2], a3 = alpha[3], a4 = alpha[4];
    size_t rb0 = ((size_t)((clampi(gz-2,0,28)*GG + gy)*GG + gx)) * DD3;
    size_t rb1 = ((size_t)((clampi(gz-1,0,28)*GG + gy)*GG + gx)) * DD3;
    size_t rb2 = ((size_t)((gz*GG + gy)*GG + gx)) * DD3;
    size_t rb3 = ((size_t)((clampi(gz+1,0,28)*GG + gy)*GG + gx)) * DD3;
    size_t rb4 = ((size_t)((clampi(gz+2,0,28)*GG + gy)*GG + gx)) * DD3;
    const float* drow = dcin + (size_t)g * DD3;
    float v[15];
    if (tid < 225) {
        #pragma unroll
        for (int z = 0; z < 15; ++z) {
            int d = z*225 + tid;
            float ca = MW0*(t2[rb0+d] + t2[rb4+d]) + MW1*(t2[rb1+d] + t2[rb3+d])
                     + MW2*t2[rb2+d];
            v[z] = a4 + a2 * drow[d] + a3 * ca;
        }
    }
    minavg_cols(U, V, v, tid, c3out + (size_t)g * DD3);
}

// ---------------- K7: z-conv of t4 -> softmax -> cost_soft + pred_xyz ----------------
__global__ void __launch_bounds__(256) k_zsoftmax(const float* __restrict__ t4,
                                                  const float* __restrict__ alpha,
                                                  float* __restrict__ cost,
                                                  float* __restrict__ pred) {
    __shared__ float row[DD3];
    __shared__ float4 red4[256];
    int tid = threadIdx.x;
    int g = blockIdx.x;
    int gx = g % GG; int gy = (g / GG) % GG; int gz = g / GG2;
    float a5 = alpha[5];
    size_t rb0 = ((size_t)((clampi(gz-2,0,28)*GG + gy)*GG + gx)) * DD3;
    size_t rb1 = ((size_t)((clampi(gz-1,0,28)*GG + gy)*GG + gx)) * DD3;
    size_t rb2 = ((size_t)((gz*GG + gy)*GG + gx)) * DD3;
    size_t rb3 = ((size_t)((clampi(gz+1,0,28)*GG + gy)*GG + gx)) * DD3;
    size_t rb4 = ((size_t)((clampi(gz+2,0,28)*GG + gy)*GG + gx)) * DD3;

    float lmax = -3.0e38f;
    for (int d = tid; d < DD3; d += 256) {
        float ca = MW0*(t4[rb0+d] + t4[rb4+d]) + MW1*(t4[rb1+d] + t4[rb3+d]) + MW2*t4[rb2+d];
        float vv = -a5 * ca;
        row[d] = vv;
        lmax = fmaxf(lmax, vv);
    }
    red4[tid].x = lmax;
    __syncthreads();
    for (int s = 128; s > 0; s >>= 1) {
        if (tid < s) red4[tid].x = fmaxf(red4[tid].x, red4[tid + s].x);
        __syncthreads();
    }
    float m = red4[0].x;
    __syncthreads();

    float s0 = 0.f, s1 = 0.f, s2 = 0.f, s3 = 0.f;
    for (int d = tid; d < DD3; d += 256) {
        float p = expf(row[d] - m);
        row[d] = p;
        int jx = d % 15; int r = d / 15; int jy = r % 15; int jz = r / 15;
        s0 += p;
        s1 += p * (0.4f * ((2.0f * jx + 1.0f) / 15.0f - 1.0f));
        s2 += p * (0.4f * ((2.0f * jy + 1.0f) / 15.0f - 1.0f));
        s3 += p * (0.4f * ((2.0f * jz + 1.0f) / 15.0f - 1.0f));
    }
    red4[tid] = make_float4(s0, s1, s2, s3);
    __syncthreads();
    for (int s = 128; s > 0; s >>= 1) {
        if (tid < s) {
            float4 a = red4[tid], b = red4[tid + s];
            red4[tid] = make_float4(a.x + b.x, a.y + b.y, a.z + b.z, a.w + b.w);
        }
        __syncthreads();
    }
    float4 tot = red4[0];
    float inv = 1.0f / tot.x;
    size_t base = (size_t)g * DD3;
    for (int d = tid; d < DD3; d += 256) cost[base + d] = row[d] * inv;
    if (tid == 0) {
        pred[g*3 + 0] = tot.y * inv;
        pred[g*3 + 1] = tot.z * inv;
        pred[g*3 + 2] = tot.w * inv;
    }
}

extern "C" void kernel_launch(void* const* d_in, const int* in_sizes, int n_in,
                              void* d_out, int out_size, void* d_ws, size_t ws_size,
                              hipStream_t stream) {
    const float* feat00 = (const float*)d_in[0];
    const float* feat50 = (const float*)d_in[1];
    const float* alpha  = (const float*)d_in[2];
    float* out = (float*)d_out;
    float* ws  = (float*)d_ws;

    float* ft5  = ws;                            // [4][NVOX] float4 (FT_ELEMS floats)
    float* S0   = ws + FT_ELEMS;                 // dc -> c3 -> t4 (row-local reuse)
    float* DOUT = out;                           // scratch use of output buffer: c -> t2
    float* pred = out + (size_t)GG3 * DD3;

    size_t need = ((size_t)FT_ELEMS + (size_t)GG3 * DD3) * sizeof(float);
    if (ws_size < need) return;  // fail cleanly if workspace too small

    // moving image: voxel-major channel-quad layout for LDS window staging
    k_transpose4<<<dim3(NVOX / 256, 4), 256, 0, stream>>>(feat50, ft5);

    // dc
    k_cost4<<<GG3, 256, 0, stream>>>(ft5, feat00, alpha, S0);
    // c = minavg_disp(dc)
    k_minavg2<<<GG3, 256, 0, stream>>>(S0, DOUT);
    // avg_grid x,y on c (in-place; z-conv folded into next kernel)
    dim3 cgrid((DD3 + 255) / 256, GG2);
    k_conv_grid<<<cgrid, 256, 0, stream>>>(DOUT, DOUT, 0);
    k_conv_grid<<<cgrid, 256, 0, stream>>>(DOUT, DOUT, 1);
    // c3 = minavg_disp(a4 + a2*dc + a3*zconv(t2))
    k_zcomb2<<<GG3, 256, 0, stream>>>(DOUT, S0, alpha, S0);
    // avg_grid x,y on c3 (in-place)
    k_conv_grid<<<cgrid, 256, 0, stream>>>(S0, S0, 0);
    k_conv_grid<<<cgrid, 256, 0, stream>>>(S0, S0, 1);
    // z-conv + softmax + pred
    k_zsoftmax<<<GG3, 256, 0, stream>>>(S0, alpha, out, pred);
}